// Round 6
// baseline (131.486 us; speedup 1.0000x reference)
//
#include <hip/hip_runtime.h>
#include <math.h>

// B=4, N=128, H=W=32, C=64.  out[b][j][n] = sigmoid(wl[j,:] . mean_hw MLP(...) + bl[j])
//
// R14: REMOVE THE VGPR CAP (one variable vs R13).
// R9/R11/R12/R13 post-mortem: VGPR pinned at exactly 128 FOUR times, even
// with a ~95-reg estimated working set (R13) -> the fully-unrolled layer
// chain lets the scheduler hoist weight/bias ds_reads across layers and
// inflate live ranges up to ANY cap, then spill the long-lived pool[]
// (WRITE 11.8MB scratch, 60us, nothing saturated).
// Occupancy arithmetic says the 128 cap was pure loss: grid 512 / 256 CU
// = 2 blocks/CU x 4 waves = 8 waves/CU = 2 waves/SIMD, GRID-limited.
// 128 VGPRs would allow 16 waves/CU that the grid never supplies; 256
// VGPRs still allows the 8 we actually run. So __launch_bounds__(256,1):
// allocator free to 256 regs -> hoisting becomes latency hiding, no spill.
// Kept byte-identical (proven R13, passed, 0 bank conflicts): 16x16x16
// layout-match chaining -- C/D row=(lane>>4)*4+reg == B k=(lane>>4)*4+j,
// acc[mt] of layer l IS the ks=mt B-frag of layer l+1 after in-register
// leaky+cvt; zero activation LDS traffic; weights/biases staged once into
// LDS; bias as MFMA C-operand at ks==0; pixels prefetched one tile ahead.
// Tripwires: WRITE_SIZE ~KB; VGPR NOT pinned at a cap boundary. If still
// spilling at 256, next lever = sched_barrier(0) between layers.

typedef float  f32x4  __attribute__((ext_vector_type(4)));
typedef f32x4  f32x4a __attribute__((may_alias));
typedef __bf16 bf16x4 __attribute__((ext_vector_type(4)));
typedef bf16x4 bf16x4a __attribute__((may_alias));
typedef short  s16x4  __attribute__((ext_vector_type(4)));

static __device__ __forceinline__ f32x4 MFMA16(bf16x4 a, bf16x4 b, f32x4 c) {
    return __builtin_amdgcn_mfma_f32_16x16x16bf16_1k(
        __builtin_bit_cast(s16x4, a), __builtin_bit_cast(s16x4, b), c, 0, 0, 0);
}

static __device__ __forceinline__ bf16x4 cvt4(f32x4 v) {
    bf16x4 r;
    r[0] = (__bf16)v[0]; r[1] = (__bf16)v[1];
    r[2] = (__bf16)v[2]; r[3] = (__bf16)v[3];
    return r;
}

__global__ __launch_bounds__(256, 1) void mlp_mfma_kernel(
    const float* __restrict__ image,   // [4,3,32,32]
    const float* __restrict__ coords,  // [4,128,2]
    const float* __restrict__ w1, const float* __restrict__ b1,   // [64,7],[64]
    const float* __restrict__ w2, const float* __restrict__ b2,   // [64,64],[64]
    const float* __restrict__ w3, const float* __restrict__ b3,
    const float* __restrict__ w4, const float* __restrict__ b4,
    const float* __restrict__ w5, const float* __restrict__ b5,
    const float* __restrict__ wl, const float* __restrict__ bl,   // [3,64],[3]
    float* __restrict__ out)           // [4,3,128]
{
    // WF: [l][frag=mt*4+ks][lane] x bf16x4  = 4*16*64*4 bf16 = 32 KB
    __shared__ __align__(16) __bf16 WF[16384];
    __shared__ __align__(16) float  POOL[4][64];     // [wave][ch]  1 KB
    __shared__ float BL[320];                        // [layer][64]

    const int tid  = threadIdx.x;
    const int wave = tid >> 6;
    const int lane = tid & 63;
    const int c15  = lane & 15;
    const int q    = lane >> 4;
    const int bn   = blockIdx.x;
    const int b    = bn >> 7;

    // ---- stage weight A-frags (bf16) into LDS: wave w converts layer w.
    // NO runtime-indexed array (scratch hazard): wave-uniform ternary.
    {
        const float* Wsrc = (wave == 0) ? w2 : (wave == 1) ? w3
                          : (wave == 2) ? w4 : w5;
        #pragma unroll
        for (int f = 0; f < 16; ++f) {
            const int mt = f >> 2, ks = f & 3;
            f32x4 v = *(const f32x4a*)(Wsrc + (mt * 16 + c15) * 64 + ks * 16 + 4 * q);
            *(bf16x4a*)&WF[((wave * 16 + f) * 64 + lane) * 4] = cvt4(v);
        }
    }
    if (tid < 64) {
        BL[tid]       = b1[tid];
        BL[64 + tid]  = b2[tid];
        BL[128 + tid] = b3[tid];
        BL[192 + tid] = b4[tid];
        BL[256 + tid] = b5[tid];
    }
    __syncthreads();

    // ---- layer-1 A-frags (K=16, channels 0..6 used): w1[row][k], k=4q+j
    bf16x4 a1[4];
    #pragma unroll
    for (int mt = 0; mt < 4; ++mt)
        #pragma unroll
        for (int j = 0; j < 4; ++j) {
            const int k = 4 * q + j;
            float v = (k < 7) ? w1[(mt * 16 + c15) * 7 + k] : 0.0f;
            a1[mt][j] = (__bf16)v;
        }

    const float cx = coords[2 * bn + 0];
    const float cy = coords[2 * bn + 1];
    const float* img = image + b * 3072;

    // ---- loop-invariant pieces of the layer-1 B-fragment.
    // Wave pixels: hw = wave*256 + t*16 + c15, t=0..15.
    // row = wave*8 + (t>>1); col = (t&1)*16 + c15.
    // B1 lane (q,c15): q=0 -> [img0,img1,img2,row], q=1 -> [col,cx,cy,0], else 0.
    const float inv31 = 1.0f / 31.0f;
    const bool  q0  = (q == 0);
    const float g0e = (q == 1) ? (float)c15 * inv31        : 0.0f;
    const float g0o = (q == 1) ? (float)(c15 + 16) * inv31 : 0.0f;
    const float g1  = (q == 1) ? cx : 0.0f;
    const float g2  = (q == 1) ? cy : 0.0f;

    f32x4 pool[4];
    #pragma unroll
    for (int mt = 0; mt < 4; ++mt) pool[mt] = (f32x4){0.f, 0.f, 0.f, 0.f};

    // prefetch pixels for tile 0
    float p0, p1, p2;
    {
        const int hw = wave * 256 + c15;
        p0 = img[hw]; p1 = img[1024 + hw]; p2 = img[2048 + hw];
    }

    #pragma unroll 1
    for (int t = 0; t < 16; ++t) {      // 16 tiles x 16 px per wave
        // ---- build layer-1 B fragment from prefetched pixels
        const float rowv = (float)(wave * 8 + (t >> 1)) * inv31;
        bf16x4 B1;
        B1[0] = (__bf16)(q0 ? p0 : ((t & 1) ? g0o : g0e));
        B1[1] = (__bf16)(q0 ? p1 : g1);
        B1[2] = (__bf16)(q0 ? p2 : g2);
        B1[3] = (__bf16)(q0 ? rowv : 0.0f);

        // ---- prefetch next tile's pixels
        {
            const int tt = (t < 15) ? (t + 1) : 15;
            const int hw = wave * 256 + tt * 16 + c15;
            p0 = img[hw]; p1 = img[1024 + hw]; p2 = img[2048 + hw];
        }

        // ======== layer 1 (bias as C operand) ========
        f32x4 acc[4];
        {
            f32x4 bv[4];
            #pragma unroll
            for (int mt = 0; mt < 4; ++mt)
                bv[mt] = *(const f32x4a*)&BL[mt * 16 + 4 * q];
            #pragma unroll
            for (int mt = 0; mt < 4; ++mt)
                acc[mt] = MFMA16(a1[mt], B1, bv[mt]);
        }

        // ======== layers 2..5 — register-chained acts, LDS weights ========
        #pragma unroll
        for (int l = 0; l < 4; ++l) {
            // transition: leaky + cvt; acc[mt] -> B-fragment ks=mt (same lane!)
            bf16x4 Bf[4];
            #pragma unroll
            for (int mt = 0; mt < 4; ++mt) {
                f32x4 v = acc[mt];
                #pragma unroll
                for (int r = 0; r < 4; ++r) v[r] = fmaxf(v[r], 0.1f * v[r]);
                Bf[mt] = cvt4(v);
            }
            f32x4 bv[4];
            #pragma unroll
            for (int mt = 0; mt < 4; ++mt)
                bv[mt] = *(const f32x4a*)&BL[(l + 1) * 64 + mt * 16 + 4 * q];
            #pragma unroll
            for (int ks = 0; ks < 4; ++ks) {
                bf16x4 af[4];
                #pragma unroll
                for (int mt = 0; mt < 4; ++mt)
                    af[mt] = *(const bf16x4a*)
                        &WF[((l * 16 + mt * 4 + ks) * 64 + lane) * 4];
                #pragma unroll
                for (int mt = 0; mt < 4; ++mt)
                    acc[mt] = MFMA16(af[mt], Bf[ks],
                                     (ks == 0) ? bv[mt] : acc[mt]);
            }
        }

        // ---- final leaky + pool accumulate (registers only)
        #pragma unroll
        for (int mt = 0; mt < 4; ++mt)
            #pragma unroll
            for (int r = 0; r < 4; ++r) {
                const float v = acc[mt][r];
                pool[mt][r] += fmaxf(v, 0.1f * v);
            }
    }

    // ---- in-wave pre-reduce over the 16 pixel-columns (c15 bits 0..3)
    #pragma unroll
    for (int mt = 0; mt < 4; ++mt)
        #pragma unroll
        for (int r = 0; r < 4; ++r) {
            float v = pool[mt][r];
            v += __shfl_xor(v, 1, 64);
            v += __shfl_xor(v, 2, 64);
            v += __shfl_xor(v, 4, 64);
            v += __shfl_xor(v, 8, 64);
            pool[mt][r] = v;
        }
    if (c15 == 0) {
        #pragma unroll
        for (int mt = 0; mt < 4; ++mt)
            *(f32x4a*)&POOL[wave][mt * 16 + 4 * q] = pool[mt];
    }

    __syncthreads();

    // ---- block reduce (4 waves) + head + sigmoid
    if (tid < 64) {
        const int c = tid;
        float s = 0.0f;
        #pragma unroll
        for (int w = 0; w < 4; ++w) s += POOL[w][c];
        const float p = s * (1.0f / 1024.0f);
        float s0 = wl[c] * p;
        float s1 = wl[64 + c] * p;
        float s2 = wl[128 + c] * p;
        #pragma unroll
        for (int off = 32; off > 0; off >>= 1) {
            s0 += __shfl_down(s0, off, 64);
            s1 += __shfl_down(s1, off, 64);
            s2 += __shfl_down(s2, off, 64);
        }
        if (c == 0) {
            const int n = bn & 127;
            out[(b * 3 + 0) * 128 + n] = 1.0f / (1.0f + expf(-(bl[0] + s0)));
            out[(b * 3 + 1) * 128 + n] = 1.0f / (1.0f + expf(-(bl[1] + s1)));
            out[(b * 3 + 2) * 128 + n] = 1.0f / (1.0f + expf(-(bl[2] + s2)));
        }
    }
}

extern "C" void kernel_launch(void* const* d_in, const int* in_sizes, int n_in,
                              void* d_out, int out_size, void* d_ws, size_t ws_size,
                              hipStream_t stream) {
    const float* image  = (const float*)d_in[0];
    const float* coords = (const float*)d_in[1];
    const float* w1 = (const float*)d_in[2];
    const float* b1 = (const float*)d_in[3];
    const float* w2 = (const float*)d_in[4];
    const float* b2 = (const float*)d_in[5];
    const float* w3 = (const float*)d_in[6];
    const float* b3 = (const float*)d_in[7];
    const float* w4 = (const float*)d_in[8];
    const float* b4 = (const float*)d_in[9];
    const float* w5 = (const float*)d_in[10];
    const float* b5 = (const float*)d_in[11];
    const float* wl = (const float*)d_in[12];
    const float* bl = (const float*)d_in[13];
    float* out = (float*)d_out;

    mlp_mfma_kernel<<<dim3(512), dim3(256), 0, stream>>>(
        image, coords, w1, b1, w2, b2, w3, b3, w4, b4, w5, b5, wl, bl, out);
}